// Round 10
// baseline (191.491 us; speedup 1.0000x reference)
//
#include <hip/hip_runtime.h>
#include <math.h>

#define B_  2
#define S_  2048
#define D_  1024
#define H_  16
#define HD_ 64
#define M_  (B_*S_)

typedef unsigned short ushort_t;
typedef unsigned int   uint_t;
typedef __attribute__((ext_vector_type(8))) short bf16x8;
typedef __attribute__((ext_vector_type(4))) float f32x4;

__device__ __forceinline__ ushort_t f2bf(float f) {
    uint_t u = __builtin_bit_cast(uint_t, f);
    u += 0x7FFFu + ((u >> 16) & 1u);           // RNE
    return (ushort_t)(u >> 16);
}
__device__ __forceinline__ float bf2f(ushort_t h) {
    uint_t u = (uint_t)h << 16;
    return __builtin_bit_cast(float, u);
}
// truncating pack: two f32 -> (bf16(lo) | bf16(hi)<<16), one v_perm_b32
__device__ __forceinline__ uint_t pkt(float lo, float hi) {
    return __builtin_amdgcn_perm(__builtin_bit_cast(uint_t, hi),
                                 __builtin_bit_cast(uint_t, lo), 0x07060302u);
}
// async global->LDS, 16B per lane; lds addr = wave-uniform base + lane*16
__device__ __forceinline__ void dma16(const ushort_t* g, ushort_t* l) {
    __builtin_amdgcn_global_load_lds(
        (const __attribute__((address_space(1))) uint_t*)g,
        (__attribute__((address_space(3))) uint_t*)l, 16, 0, 0);
}
// swizzled fragment read from unpadded [row][64] bf16 tile
__device__ __forceinline__ bf16x8 fragr(const ushort_t* base, int row, int chunk) {
    return *(const bf16x8*)&base[row * 64 + (((chunk ^ (row & 7)) << 3))];
}

// ---------------------------------------------------------------------------
// prep: blocks [0,3072) = weight transpose+cvt (W [K][N] f32 -> WT [N][K] bf16)
//       blocks [3072,7168) = q f32 -> bf16
// ---------------------------------------------------------------------------
__global__ __launch_bounds__(256)
void prep(const float* __restrict__ W0, const float* __restrict__ W1,
          const float* __restrict__ W2, ushort_t* __restrict__ T0,
          ushort_t* __restrict__ T1, ushort_t* __restrict__ T2,
          const float* __restrict__ X, ushort_t* __restrict__ Y) {
    const int bx = blockIdx.x;
    if (bx >= 3072) {
        const int i = ((bx - 3072) * 256 + threadIdx.x) * 4;
        float4 x = *(const float4*)(X + i);
        *(ushort4*)(Y + i) = make_ushort4(f2bf(x.x), f2bf(x.y), f2bf(x.z), f2bf(x.w));
        return;
    }
    __shared__ float T[32][36];
    const int z = bx >> 10;
    const float*  W  = (z == 0) ? W0 : (z == 1) ? W1 : W2;
    ushort_t*     WT = (z == 0) ? T0 : (z == 1) ? T1 : T2;
    const int kt = bx & 31, nt = (bx >> 5) & 31;
    const int t = threadIdx.x;
    const int rr = t >> 3, cc = (t & 7) * 4;
    float4 w4 = *(const float4*)(W + (size_t)(kt * 32 + rr) * D_ + nt * 32 + cc);
    T[rr][cc + 0] = w4.x; T[rr][cc + 1] = w4.y; T[rr][cc + 2] = w4.z; T[rr][cc + 3] = w4.w;
    __syncthreads();
    ushort_t o[4];
    #pragma unroll
    for (int j = 0; j < 4; ++j) o[j] = f2bf(T[cc + j][rr]);
    *(ushort4*)(WT + (size_t)(nt * 32 + rr) * D_ + kt * 32 + cc) =
        make_ushort4(o[0], o[1], o[2], o[3]);
}

// ---------------------------------------------------------------------------
// Merged launch: blocks [0,512) = fused dual GEMM + chunk-scan epilogue
// (XCD-swizzled); blocks [512,1536) = kv_cvt_g (inputs-only, backfills the
// latency-bound dual — its memory traffic rides in the dual's BW headroom).
// ---------------------------------------------------------------------------
__global__ __launch_bounds__(256)
void gemm_dual_kv(const ushort_t* __restrict__ A, const ushort_t* __restrict__ BTi,
                  const ushort_t* __restrict__ BTg, const float* __restrict__ bi,
                  const float* __restrict__ bg, uint_t* __restrict__ PH,
                  float* __restrict__ cA, float* __restrict__ cU,
                  const float* __restrict__ K, const float* __restrict__ V,
                  const float* __restrict__ gammas, ushort_t* __restrict__ Kb,
                  ushort_t* __restrict__ VT, float* __restrict__ Gg) {
    __shared__ ushort_t smem[32768];   // 64 KB
    const int tid = threadIdx.x;
    const int w = tid >> 6, lane = tid & 63, quad = lane >> 4, l15 = lane & 15;

    if (blockIdx.x >= 512) {
        // ---------------- kv_cvt_g role ----------------
        ushort_t* Tv = smem;               // [val][ml]  64*72
        ushort_t* Tk = smem + 64 * 72;     // [kappa][ml] 64*72
        const int idx = blockIdx.x - 512;
        const int mt = idx & 31, h = (idx >> 5) & 15, b = idx >> 9;
        const int m0 = mt * 64;
        const int r = tid >> 2, c0 = (tid & 3) * 16;
        const float lg = log2f(gammas[h]);
        const float gm = exp2f(-(float)r * lg);   // gamma^{-ml}, ml = r
        {
            const float* src = K + ((size_t)(b * S_ + m0 + r)) * D_ + h * HD_ + c0;
            ushort_t kb[16];
            #pragma unroll
            for (int j4 = 0; j4 < 4; ++j4) {
                float4 x = *(const float4*)(src + j4 * 4);
                kb[j4 * 4 + 0] = f2bf(x.x); kb[j4 * 4 + 1] = f2bf(x.y);
                kb[j4 * 4 + 2] = f2bf(x.z); kb[j4 * 4 + 3] = f2bf(x.w);
            }
            ushort_t* dst = Kb + ((size_t)(b * S_ + m0 + r)) * D_ + h * HD_ + c0;
            *(uint4*)(dst + 0) = *(const uint4*)&kb[0];
            *(uint4*)(dst + 8) = *(const uint4*)&kb[8];
            #pragma unroll
            for (int j = 0; j < 16; ++j) Tk[(c0 + j) * 72 + r] = kb[j];
        }
        {
            const float* src = V + ((size_t)(b * S_ + m0 + r)) * D_ + h * HD_ + c0;
            #pragma unroll
            for (int j4 = 0; j4 < 4; ++j4) {
                float4 x = *(const float4*)(src + j4 * 4);
                Tv[(c0 + j4 * 4 + 0) * 72 + r] = f2bf(x.x * gm);
                Tv[(c0 + j4 * 4 + 1) * 72 + r] = f2bf(x.y * gm);
                Tv[(c0 + j4 * 4 + 2) * 72 + r] = f2bf(x.z * gm);
                Tv[(c0 + j4 * 4 + 3) * 72 + r] = f2bf(x.w * gm);
            }
        }
        __syncthreads();
        {
            ushort_t* dst = VT + ((size_t)((b * H_ + h) * HD_ + r)) * S_ + m0 + c0;
            *(uint4*)(dst + 0) = *(const uint4*)&Tv[r * 72 + c0 + 0];
            *(uint4*)(dst + 8) = *(const uint4*)&Tv[r * 72 + c0 + 8];
        }
        // G^T = Tv . Tk^T via MFMA
        bf16x8 af0 = *(const bf16x8*)&Tv[(w * 16 + l15) * 72 + quad * 8];
        bf16x8 af1 = *(const bf16x8*)&Tv[(w * 16 + l15) * 72 + 32 + quad * 8];
        float* gout = Gg + ((size_t)((b * H_ + h) * 32 + mt)) * 4096;
        #pragma unroll
        for (int kt2 = 0; kt2 < 4; ++kt2) {
            bf16x8 bf0 = *(const bf16x8*)&Tk[(kt2 * 16 + l15) * 72 + quad * 8];
            bf16x8 bf1 = *(const bf16x8*)&Tk[(kt2 * 16 + l15) * 72 + 32 + quad * 8];
            f32x4 g = {};
            g = __builtin_amdgcn_mfma_f32_16x16x32_bf16(af0, bf0, g, 0, 0, 0);
            g = __builtin_amdgcn_mfma_f32_16x16x32_bf16(af1, bf1, g, 0, 0, 0);
            #pragma unroll
            for (int reg = 0; reg < 4; ++reg)
                gout[(w * 16 + quad * 4 + reg) * 64 + kt2 * 16 + l15] = g[reg];
        }
        return;
    }

    // ---------------- dual GEMM + scan role --------------
    const int swz = (blockIdx.x & 7) * 64 + (blockIdx.x >> 3);
    const int n0 = (swz & 15) * 64, m0 = (swz >> 4) * 128;
    const int wr = (w >> 1) * 64, wc = (w & 1) * 32;
    const int l8 = lane & 7, lr8 = lane >> 3;

    f32x4 acc_i[4][2] = {};
    f32x4 acc_g[4][2] = {};

    auto stage = [&](int k0, int bufo) {
        #pragma unroll
        for (int t = 0; t < 4; ++t) {
            const int row = w * 32 + t * 8 + lr8;
            const int gc = ((l8 ^ (row & 7)) << 3);
            dma16(A + (size_t)(m0 + row) * D_ + k0 + gc, &smem[bufo + row * 64 + l8 * 8]);
        }
        #pragma unroll
        for (int t = 0; t < 2; ++t) {
            const int row = w * 16 + t * 8 + lr8;
            const int gc = ((l8 ^ (row & 7)) << 3);
            dma16(BTi + (size_t)(n0 + row) * D_ + k0 + gc, &smem[bufo + 8192 + row * 64 + l8 * 8]);
            dma16(BTg + (size_t)(n0 + row) * D_ + k0 + gc, &smem[bufo + 12288 + row * 64 + l8 * 8]);
        }
    };

    stage(0, 0);
    __syncthreads();
    for (int t = 0; t < 16; ++t) {
        const int bufo = (t & 1) * 16384;
        if (t < 15) stage((t + 1) * 64, 16384 - bufo);
        const ushort_t* As = smem + bufo;
        const ushort_t* Bi = smem + bufo + 8192;
        const ushort_t* Bg = smem + bufo + 12288;
        #pragma unroll
        for (int kk = 0; kk < 2; ++kk) {
            bf16x8 af[4], bfi[2], bfg[2];
            #pragma unroll
            for (int i = 0; i < 4; ++i)
                af[i] = fragr(As, wr + 16 * i + l15, kk * 4 + quad);
            #pragma unroll
            for (int j = 0; j < 2; ++j) {
                bfi[j] = fragr(Bi, wc + 16 * j + l15, kk * 4 + quad);
                bfg[j] = fragr(Bg, wc + 16 * j + l15, kk * 4 + quad);
            }
            #pragma unroll
            for (int i = 0; i < 4; ++i)
                #pragma unroll
                for (int j = 0; j < 2; ++j) {
                    acc_i[i][j] = __builtin_amdgcn_mfma_f32_16x16x32_bf16(
                        af[i], bfi[j], acc_i[i][j], 0, 0, 0);
                    acc_g[i][j] = __builtin_amdgcn_mfma_f32_16x16x32_bf16(
                        af[i], bfg[j], acc_g[i][j], 0, 0, 0);
                }
        }
        __syncthreads();
    }

    // epilogue: reuse staging LDS. Us bf16, Gu u16 fixed-point gate.
    ushort_t* Us = smem;
    ushort_t* Gu = smem + 8448;
    #pragma unroll
    for (int j = 0; j < 2; ++j) {
        const int n = wc + 16 * j + l15;
        const float bbi = bi[n0 + n], bbg = bg[n0 + n];
        #pragma unroll
        for (int i = 0; i < 4; ++i) {
            #pragma unroll
            for (int r = 0; r < 4; ++r) {
                const int m = wr + 16 * i + quad * 4 + r;
                Us[m * 66 + n] = f2bf(acc_i[i][j][r] + bbi);
                float g = 1.0f / (1.0f + __expf(-(acc_g[i][j][r] + bbg)));
                Gu[m * 66 + n] = (ushort_t)__float2uint_rn(g * 65535.0f);
            }
        }
    }
    __syncthreads();

    const int nl = tid & 63, c = tid >> 6;
    const int gmb = m0 + c * 32;
    const size_t gbase = (size_t)gmb * D_ + n0 + nl;
    float Aa = 1.0f, hh = 0.0f;
    #pragma unroll 4
    for (int j = 0; j < 32; ++j) {
        const float g = (float)Gu[(c * 32 + j) * 66 + nl] * (1.0f / 65535.0f);
        const float u = bf2f(Us[(c * 32 + j) * 66 + nl]);
        Aa *= g;
        hh = fmaf(g, hh, u);
        PH[gbase + (size_t)j * D_] = (uint_t)f2bf(Aa) | ((uint_t)f2bf(hh) << 16);
    }
    const int bb = gmb >> 11;
    const int ch = (gmb & 2047) >> 5;
    const int ci = ((bb * 64 + ch) << 10) + n0 + nl;
    cA[ci] = Aa;
    cU[ci] = hh;
}

// ---------------------------------------------------------------------------
// mid_scan: blocks [0,512) = state scan, 1 float/thread (4x waves vs float4
// variant -> G loads fully prefetch under the serial fma chain);
// blocks [512,520) = chunk-level gated scan -> carry-ins.
// ---------------------------------------------------------------------------
__global__ __launch_bounds__(256)
void mid_scan(const float* __restrict__ Gg, const float* __restrict__ gammas,
              ushort_t* __restrict__ Sb, const float* __restrict__ cA,
              const float* __restrict__ cU, float* __restrict__ cIn) {
    const int bi = blockIdx.x;
    if (bi < 512) {
        const int bh = bi >> 4;                 // (b*H + h) in [0,32)
        const int h = bh & 15;
        const int e = (bi & 15) * 256 + threadIdx.x;   // entry in [0,4096)
        const float g64 = exp2f(64.0f * log2f(gammas[h]));
        const size_t base = (size_t)bh * 32 * 4096 + e;
        float S = 0.0f;
        #pragma unroll
        for (int c = 0; c < 32; ++c) {
            Sb[base + (size_t)c * 4096] = f2bf(S);
            const float G = Gg[base + (size_t)c * 4096];
            S = g64 * (S + G);
        }
        return;
    }
    const int t = (bi - 512) * 256 + threadIdx.x;   // 0..2047
    const int d = t & 1023, b = t >> 10;
    float h = 0.0f;
    for (int c0 = 0; c0 < 64; c0 += 16) {
        float Av[16], Uv[16];
        #pragma unroll
        for (int j = 0; j < 16; ++j) {
            const int idx = ((b * 64 + c0 + j) << 10) + d;
            Av[j] = cA[idx]; Uv[j] = cU[idx];
        }
        #pragma unroll
        for (int j = 0; j < 16; ++j) {
            cIn[((b * 64 + c0 + j) << 10) + d] = h;
            h = fmaf(Av[j], h, Uv[j]);
        }
    }
}

// ---------------------------------------------------------------------------
// Fused W_out GEMM + retention, XCD-swizzled, with hidden retention staging.
// scan_fix is folded into the A-staging: stage PH (packed P,h_local) + cIn,
// compute h = f2bf(fmaf(ci, P, hl)) in flight (bit-identical to the old
// scan_fix output), ds_write into the same swizzled LDS slots. Removes the
// scan_fix launch + its 24 MB round-trip.
// ---------------------------------------------------------------------------
__global__ __launch_bounds__(256)
void gemm_out_ret(const uint_t* __restrict__ PH, const float* __restrict__ cIn,
                  const ushort_t* __restrict__ BT, const float* __restrict__ bias,
                  const ushort_t* __restrict__ Kb, const ushort_t* __restrict__ VT,
                  const ushort_t* __restrict__ Sb, const float* __restrict__ gammas,
                  float* __restrict__ Out) {
    __shared__ ushort_t smem[24576];   // 48 KB
    const int tid = threadIdx.x;
    const int flat = blockIdx.x + (blockIdx.y << 4);
    const int swz = (flat & 7) * 64 + (flat >> 3);
    const int h = swz & 15;                   // head
    const int n0 = h * 64, m0 = (swz >> 4) * 128;
    const int w = tid >> 6, lane = tid & 63, quad = lane >> 4, l15 = lane & 15;
    const int wr = (w >> 1) * 64, wc = (w & 1) * 32;
    const int l8 = lane & 7, lr8 = lane >> 3;

    ushort_t* Qs = smem;
    ushort_t* Ks = smem + 8192;
    ushort_t* Vt = smem + 12288;
    ushort_t* Ss = smem + 16384;
    ushort_t* Ps = smem + 20480;

    auto stageK = [&](int sc) {
        const int mrow = m0 + sc * 64;
        const size_t bS2 = (size_t)(mrow >> 11) * S_;
        const int s0r = mrow & 2047;
        #pragma unroll
        for (int t2 = 0; t2 < 2; ++t2) {
            const int row = w * 16 + t2 * 8 + lr8;
            const int gc = ((l8 ^ (row & 7)) << 3);
            dma16(Kb + (bS2 + s0r + row) * D_ + h * HD_ + gc, &Ks[row * 64 + l8 * 8]);
        }
    };
    auto stageV = [&](int sc) {
        const int mrow = m0 + sc * 64;
        const size_t vrow0 = (size_t)(((mrow >> 11) * H_ + h) * HD_);
        const int s0r = mrow & 2047;
        #pragma unroll
        for (int t2 = 0; t2 < 2; ++t2) {
            const int row = w * 16 + t2 * 8 + lr8;
            const int gc = ((l8 ^ (row & 7)) << 3);
            dma16(VT + (vrow0 + row) * S_ + s0r + gc, &Vt[row * 64 + l8 * 8]);
        }
    };
    auto stageS = [&](int sc) {
        const int mrow = m0 + sc * 64;
        const size_t sbase = ((size_t)(((mrow >> 11) * H_ + h) * 32 + ((mrow & 2047) >> 6))) * 4096;
        #pragma unroll
        for (int t2 = 0; t2 < 2; ++t2) {
            const int row = w * 16 + t2 * 8 + lr8;
            const int gc = ((l8 ^ (row & 7)) << 3);
            dma16(Sb + sbase + (size_t)row * 64 + gc, &Ss[row * 64 + l8 * 8]);
        }
    };

    f32x4 acc[4][2] = {};

    // A-staging with in-flight scan_fix: per t-group load 8 packed PH dwords +
    // 8 cIn floats, compute 8 bf16 h values, ds_write_b128 to the swizzled slot.
    auto stage = [&](int k0, int bufo) {
        #pragma unroll
        for (int t = 0; t < 4; ++t) {
            const int row = w * 32 + t * 8 + lr8;
            const int gc = ((l8 ^ (row & 7)) << 3);
            const int m = m0 + row;
            const int bb = m >> 11;
            const int ch = (m & 2047) >> 5;
            const uint_t* phs = PH + (size_t)m * D_ + k0 + gc;
            const float* cis = cIn + (((bb * 64 + ch) << 10) + k0 + gc);
            uint4 ph0 = *(const uint4*)(phs + 0);
            uint4 ph1 = *(const uint4*)(phs + 4);
            float4 ci0 = *(const float4*)(cis + 0);
            float4 ci1 = *(const float4*)(cis + 4);
            ushort_t hv[8];
            hv[0] = f2bf(fmaf(ci0.x, bf2f((ushort_t)(ph0.x & 0xFFFF)), bf2f((ushort_t)(ph0.x >> 16))));
            hv[1] = f2bf(fmaf(ci0.y, bf2f((ushort_t)(ph0.y & 0xFFFF)), bf2f((ushort_t)(ph0.y >> 16))));
            hv[2] = f2bf(fmaf(ci0.z, bf2f((ushort_t)(ph0.z & 0xFFFF)), bf2f((ushort_t)(ph0.z >> 16))));
            hv[3] = f2bf(fmaf(ci0.w, bf2f((ushort_t)(ph0.w & 0xFFFF)), bf2f((ushort_t)(ph0.w >> 16))));
            hv[4] = f2bf(fmaf(ci1.x, bf2f((ushort_t)(ph1.x & 0xFFFF)), bf2f((ushort_t)(ph1.x >> 16))));
            hv[5] = f2bf(fmaf(ci1.y, bf2f((ushort_t)(ph1.y & 0xFFFF)), bf2f((ushort_t)(ph1.y >> 16))));
            hv[6] = f2bf(fmaf(ci1.z, bf2f((ushort_t)(ph1.z & 0xFFFF)), bf2f((ushort_t)(ph1.z >> 16))));
            hv[7] = f2bf(fmaf(ci1.w, bf2f((ushort_t)(ph1.w & 0xFFFF)), bf2f((ushort_t)(ph1.w >> 16))));
            *(uint4*)&smem[bufo + row * 64 + l8 * 8] = *(const uint4*)&hv[0];
        }
        #pragma unroll
        for (int t = 0; t < 2; ++t) {
            const int row = w * 16 + t * 8 + lr8;
            const int gc = ((l8 ^ (row & 7)) << 3);
            dma16(BT + (size_t)(n0 + row) * D_ + k0 + gc, &smem[bufo + 8192 + row * 64 + l8 * 8]);
        }
    };

    stage(0, 0);
    __syncthreads();
    for (int t = 0; t < 16; ++t) {
        const int bufo = (t & 1) * 12288;
        if (t < 15) stage((t + 1) * 64, 12288 - bufo);
        if (t == 15) stageK(0);   // buffer0 Bs region (== Ks) dead since t=14 sync
        const ushort_t* As = smem + bufo;
        const ushort_t* Bs = smem + bufo + 8192;
        #pragma unroll
        for (int kk = 0; kk < 2; ++kk) {
            bf16x8 af[4], bf[2];
            #pragma unroll
            for (int i = 0; i < 4; ++i)
                af[i] = fragr(As, wr + 16 * i + l15, kk * 4 + quad);
            #pragma unroll
            for (int j = 0; j < 2; ++j)
                bf[j] = fragr(Bs, wc + 16 * j + l15, kk * 4 + quad);
            #pragma unroll
            for (int i = 0; i < 4; ++i)
                #pragma unroll
                for (int j = 0; j < 2; ++j)
                    acc[i][j] = __builtin_amdgcn_mfma_f32_16x16x32_bf16(
                        af[i], bf[j], acc[i][j], 0, 0, 0);
        }
        __syncthreads();
    }

    // buffer1 dead after the final sync: issue chunk-0 V/S staging now.
    stageV(0);
    stageS(0);

    // ---- qp -> Qs (retention fragment layout, swizzled) --------------------
    #pragma unroll
    for (int j = 0; j < 2; ++j) {
        const int n = wc + 16 * j + l15;
        const float bb = bias[n0 + n];
        #pragma unroll
        for (int i = 0; i < 4; ++i)
            #pragma unroll
            for (int r = 0; r < 4; ++r) {
                const int m = wr + 16 * i + quad * 4 + r;
                Qs[m * 64 + (((n >> 3) ^ (m & 7)) << 3) + (n & 7)] =
                    f2bf((acc[i][j][r] + bb) * 0.125f);
            }
    }

    const float lg = log2f(gammas[h]);
    const int nl = w * 16 + l15;

    for (int sc = 0; sc < 2; ++sc) {
        __syncthreads();   // staged K/V/S (and Qs writes) visible; vmcnt drained
        const int mrow = m0 + sc * 64;
        const size_t bS = (size_t)(mrow >> 11) * S_;
        const int s0 = mrow & 2047;
        const ushort_t* Qsub = Qs + sc * 64 * 64;

        bf16x8 qf0 = fragr(Qsub, nl, quad);
        bf16x8 qf1 = fragr(Qsub, nl, 4 + quad);

        f32x4 o[4] = {};
        #pragma unroll
        for (int ct = 0; ct < 4; ++ct) {
            bf16x8 sf0 = fragr(Ss, ct * 16 + l15, quad);
            bf16x8 sf1 = fragr(Ss, ct * 16 + l15, 4 + quad);
            o[ct] = __builtin_amdgcn_mfma_f32_16x16x32_bf16(sf0, qf0, o[ct], 0, 0, 0);
            o[ct] = __builtin_amdgcn_mfma_f32_16x16x32_bf16(sf1, qf1, o[ct], 0, 0, 0);
        }
        uint2 pw[4];
        #pragma unroll
        for (int mt2 = 0; mt2 < 4; ++mt2) {
            bf16x8 kf0 = fragr(Ks, mt2 * 16 + l15, quad);
            bf16x8 kf1 = fragr(Ks, mt2 * 16 + l15, 4 + quad);
            f32x4 s = {};
            s = __builtin_amdgcn_mfma_f32_16x16x32_bf16(kf0, qf0, s, 0, 0, 0);
            s = __builtin_amdgcn_mfma_f32_16x16x32_bf16(kf1, qf1, s, 0, 0, 0);
            const int mbase = mt2 * 16 + quad * 4;
            #pragma unroll
            for (int r = 0; r < 4; ++r)
                if (nl < mbase + r) s[r] = 0.0f;
            pw[mt2].x = pkt(s[0], s[1]); pw[mt2].y = pkt(s[2], s[3]);
        }
        __syncthreads();   // all waves done reading Ks/Ss
        if (sc == 0) { stageK(1); stageS(1); }
        #pragma unroll
        for (int mt2 = 0; mt2 < 4; ++mt2) {
            const int mbase = mt2 * 16 + quad * 4;
            const int chunk = mbase >> 3;
            *(uint2*)&Ps[nl * 64 + ((chunk ^ (nl & 7)) << 3) + (mbase & 7)] = pw[mt2];
        }
        bf16x8 pf0 = fragr(Ps, nl, quad);
        bf16x8 pf1 = fragr(Ps, nl, 4 + quad);
        #pragma unroll
        for (int ct = 0; ct < 4; ++ct) {
            bf16x8 vf0 = fragr(Vt, ct * 16 + l15, quad);
            bf16x8 vf1 = fragr(Vt, ct * 16 + l15, 4 + quad);
            o[ct] = __builtin_amdgcn_mfma_f32_16x16x32_bf16(vf0, pf0, o[ct], 0, 0, 0);
            o[ct] = __builtin_amdgcn_mfma_f32_16x16x32_bf16(vf1, pf1, o[ct], 0, 0, 0);
        }

        const float esc = exp2f((float)nl * lg);
        const size_t ob = (bS + s0 + nl) * D_ + h * HD_;
        #pragma unroll
        for (int ct = 0; ct < 4; ++ct) {
            f32x4 t = o[ct] * esc;
            *(f32x4*)(Out + ob + ct * 16 + quad * 4) = t;
        }
        __syncthreads();   // all waves done reading Vt/Ps
        if (sc == 0) stageV(1);
    }
}

// ---------------------------------------------------------------------------
extern "C" void kernel_launch(void* const* d_in, const int* in_sizes, int n_in,
                              void* d_out, int out_size, void* d_ws, size_t ws_size,
                              hipStream_t stream) {
    const float* q      = (const float*)d_in[0];
    const float* k      = (const float*)d_in[1];
    const float* v      = (const float*)d_in[2];
    const float* W_in   = (const float*)d_in[3];
    const float* b_in   = (const float*)d_in[4];
    const float* W_gate = (const float*)d_in[5];
    const float* b_gate = (const float*)d_in[6];
    const float* W_out  = (const float*)d_in[7];
    const float* b_out  = (const float*)d_in[8];
    const float* gammas = (const float*)d_in[9];
    float* out = (float*)d_out;

    char* ws = (char*)d_ws;
    const size_t MB = 1024 * 1024;
    uint_t*   PH      = (uint_t*)(ws);                // [0,16) packed (P, h_local)
    ushort_t* q_bf    = (ushort_t*)(ws + 32 * MB);    // [32,40)
    ushort_t* WT_in   = (ushort_t*)(ws + 40 * MB);
    ushort_t* WT_gate = (ushort_t*)(ws + 42 * MB);
    ushort_t* WT_out  = (ushort_t*)(ws + 44 * MB);
    float*    cA      = (float*)(ws + 46 * MB);
    float*    cU      = (float*)(ws + 46 * MB + 512 * 1024);
    float*    cIn     = (float*)(ws + 47 * MB);
    ushort_t* k_bf    = (ushort_t*)(ws + 48 * MB);    // [48,56)
    ushort_t* VT      = (ushort_t*)(ws + 56 * MB);    // [56,64)
    float*    Gg      = (float*)(ws + 64 * MB);       // [64,80)
    ushort_t* Sb      = (ushort_t*)(ws + 80 * MB);    // [80,88)

    prep<<<3072 + (M_ * D_) / (256 * 4), 256, 0, stream>>>(
        W_in, W_gate, W_out, WT_in, WT_gate, WT_out, q, q_bf);

    gemm_dual_kv<<<512 + 1024, 256, 0, stream>>>(
        q_bf, WT_in, WT_gate, b_in, b_gate, PH, cA, cU,
        k, v, gammas, k_bf, VT, Gg);

    mid_scan<<<520, 256, 0, stream>>>(Gg, gammas, Sb, cA, cU, cIn);

    gemm_out_ret<<<dim3(H_, M_ / 128), 256, 0, stream>>>(
        PH, cIn, WT_out, b_out, k_bf, VT, Sb, gammas, out);
}

// Round 11
// 178.334 us; speedup vs baseline: 1.0738x; 1.0738x over previous
//
#include <hip/hip_runtime.h>
#include <math.h>

#define B_  2
#define S_  2048
#define D_  1024
#define H_  16
#define HD_ 64
#define M_  (B_*S_)

typedef unsigned short ushort_t;
typedef unsigned int   uint_t;
typedef __attribute__((ext_vector_type(8))) short bf16x8;
typedef __attribute__((ext_vector_type(4))) float f32x4;

__device__ __forceinline__ ushort_t f2bf(float f) {
    uint_t u = __builtin_bit_cast(uint_t, f);
    u += 0x7FFFu + ((u >> 16) & 1u);           // RNE
    return (ushort_t)(u >> 16);
}
__device__ __forceinline__ float bf2f(ushort_t h) {
    uint_t u = (uint_t)h << 16;
    return __builtin_bit_cast(float, u);
}
// truncating pack: two f32 -> (bf16(lo) | bf16(hi)<<16), one v_perm_b32
__device__ __forceinline__ uint_t pkt(float lo, float hi) {
    return __builtin_amdgcn_perm(__builtin_bit_cast(uint_t, hi),
                                 __builtin_bit_cast(uint_t, lo), 0x07060302u);
}
// async global->LDS, 16B per lane; lds addr = wave-uniform base + lane*16
__device__ __forceinline__ void dma16(const ushort_t* g, ushort_t* l) {
    __builtin_amdgcn_global_load_lds(
        (const __attribute__((address_space(1))) uint_t*)g,
        (__attribute__((address_space(3))) uint_t*)l, 16, 0, 0);
}
// swizzled fragment read from unpadded [row][64] bf16 tile
__device__ __forceinline__ bf16x8 fragr(const ushort_t* base, int row, int chunk) {
    return *(const bf16x8*)&base[row * 64 + (((chunk ^ (row & 7)) << 3))];
}

// ---------------------------------------------------------------------------
// prep: blocks [0,3072) = weight transpose+cvt (W [K][N] f32 -> WT [N][K] bf16)
//       blocks [3072,7168) = q f32 -> bf16
// ---------------------------------------------------------------------------
__global__ __launch_bounds__(256)
void prep(const float* __restrict__ W0, const float* __restrict__ W1,
          const float* __restrict__ W2, ushort_t* __restrict__ T0,
          ushort_t* __restrict__ T1, ushort_t* __restrict__ T2,
          const float* __restrict__ X, ushort_t* __restrict__ Y) {
    const int bx = blockIdx.x;
    if (bx >= 3072) {
        const int i = ((bx - 3072) * 256 + threadIdx.x) * 4;
        float4 x = *(const float4*)(X + i);
        *(ushort4*)(Y + i) = make_ushort4(f2bf(x.x), f2bf(x.y), f2bf(x.z), f2bf(x.w));
        return;
    }
    __shared__ float T[32][36];
    const int z = bx >> 10;
    const float*  W  = (z == 0) ? W0 : (z == 1) ? W1 : W2;
    ushort_t*     WT = (z == 0) ? T0 : (z == 1) ? T1 : T2;
    const int kt = bx & 31, nt = (bx >> 5) & 31;
    const int t = threadIdx.x;
    const int rr = t >> 3, cc = (t & 7) * 4;
    float4 w4 = *(const float4*)(W + (size_t)(kt * 32 + rr) * D_ + nt * 32 + cc);
    T[rr][cc + 0] = w4.x; T[rr][cc + 1] = w4.y; T[rr][cc + 2] = w4.z; T[rr][cc + 3] = w4.w;
    __syncthreads();
    ushort_t o[4];
    #pragma unroll
    for (int j = 0; j < 4; ++j) o[j] = f2bf(T[cc + j][rr]);
    *(ushort4*)(WT + (size_t)(nt * 32 + rr) * D_ + kt * 32 + cc) =
        make_ushort4(o[0], o[1], o[2], o[3]);
}

// ---------------------------------------------------------------------------
// Merged launch: blocks [0,512) = fused dual GEMM + chunk-scan epilogue
// (XCD-swizzled); blocks [512,1536) = kv_cvt_g (inputs-only, backfills the
// latency-bound dual — its memory traffic rides in the dual's BW headroom).
// ---------------------------------------------------------------------------
__global__ __launch_bounds__(256)
void gemm_dual_kv(const ushort_t* __restrict__ A, const ushort_t* __restrict__ BTi,
                  const ushort_t* __restrict__ BTg, const float* __restrict__ bi,
                  const float* __restrict__ bg, uint_t* __restrict__ PH,
                  float* __restrict__ cA, float* __restrict__ cU,
                  const float* __restrict__ K, const float* __restrict__ V,
                  const float* __restrict__ gammas, ushort_t* __restrict__ Kb,
                  ushort_t* __restrict__ VT, float* __restrict__ Gg) {
    __shared__ ushort_t smem[32768];   // 64 KB
    const int tid = threadIdx.x;
    const int w = tid >> 6, lane = tid & 63, quad = lane >> 4, l15 = lane & 15;

    if (blockIdx.x >= 512) {
        // ---------------- kv_cvt_g role ----------------
        ushort_t* Tv = smem;               // [val][ml]  64*72
        ushort_t* Tk = smem + 64 * 72;     // [kappa][ml] 64*72
        const int idx = blockIdx.x - 512;
        const int mt = idx & 31, h = (idx >> 5) & 15, b = idx >> 9;
        const int m0 = mt * 64;
        const int r = tid >> 2, c0 = (tid & 3) * 16;
        const float lg = log2f(gammas[h]);
        const float gm = exp2f(-(float)r * lg);   // gamma^{-ml}, ml = r
        {
            const float* src = K + ((size_t)(b * S_ + m0 + r)) * D_ + h * HD_ + c0;
            ushort_t kb[16];
            #pragma unroll
            for (int j4 = 0; j4 < 4; ++j4) {
                float4 x = *(const float4*)(src + j4 * 4);
                kb[j4 * 4 + 0] = f2bf(x.x); kb[j4 * 4 + 1] = f2bf(x.y);
                kb[j4 * 4 + 2] = f2bf(x.z); kb[j4 * 4 + 3] = f2bf(x.w);
            }
            ushort_t* dst = Kb + ((size_t)(b * S_ + m0 + r)) * D_ + h * HD_ + c0;
            *(uint4*)(dst + 0) = *(const uint4*)&kb[0];
            *(uint4*)(dst + 8) = *(const uint4*)&kb[8];
            #pragma unroll
            for (int j = 0; j < 16; ++j) Tk[(c0 + j) * 72 + r] = kb[j];
        }
        {
            const float* src = V + ((size_t)(b * S_ + m0 + r)) * D_ + h * HD_ + c0;
            #pragma unroll
            for (int j4 = 0; j4 < 4; ++j4) {
                float4 x = *(const float4*)(src + j4 * 4);
                Tv[(c0 + j4 * 4 + 0) * 72 + r] = f2bf(x.x * gm);
                Tv[(c0 + j4 * 4 + 1) * 72 + r] = f2bf(x.y * gm);
                Tv[(c0 + j4 * 4 + 2) * 72 + r] = f2bf(x.z * gm);
                Tv[(c0 + j4 * 4 + 3) * 72 + r] = f2bf(x.w * gm);
            }
        }
        __syncthreads();
        {
            ushort_t* dst = VT + ((size_t)((b * H_ + h) * HD_ + r)) * S_ + m0 + c0;
            *(uint4*)(dst + 0) = *(const uint4*)&Tv[r * 72 + c0 + 0];
            *(uint4*)(dst + 8) = *(const uint4*)&Tv[r * 72 + c0 + 8];
        }
        // G^T = Tv . Tk^T via MFMA
        bf16x8 af0 = *(const bf16x8*)&Tv[(w * 16 + l15) * 72 + quad * 8];
        bf16x8 af1 = *(const bf16x8*)&Tv[(w * 16 + l15) * 72 + 32 + quad * 8];
        float* gout = Gg + ((size_t)((b * H_ + h) * 32 + mt)) * 4096;
        #pragma unroll
        for (int kt2 = 0; kt2 < 4; ++kt2) {
            bf16x8 bf0 = *(const bf16x8*)&Tk[(kt2 * 16 + l15) * 72 + quad * 8];
            bf16x8 bf1 = *(const bf16x8*)&Tk[(kt2 * 16 + l15) * 72 + 32 + quad * 8];
            f32x4 g = {};
            g = __builtin_amdgcn_mfma_f32_16x16x32_bf16(af0, bf0, g, 0, 0, 0);
            g = __builtin_amdgcn_mfma_f32_16x16x32_bf16(af1, bf1, g, 0, 0, 0);
            #pragma unroll
            for (int reg = 0; reg < 4; ++reg)
                gout[(w * 16 + quad * 4 + reg) * 64 + kt2 * 16 + l15] = g[reg];
        }
        return;
    }

    // ---------------- dual GEMM + scan role --------------
    const int swz = (blockIdx.x & 7) * 64 + (blockIdx.x >> 3);
    const int n0 = (swz & 15) * 64, m0 = (swz >> 4) * 128;
    const int wr = (w >> 1) * 64, wc = (w & 1) * 32;
    const int l8 = lane & 7, lr8 = lane >> 3;

    f32x4 acc_i[4][2] = {};
    f32x4 acc_g[4][2] = {};

    auto stage = [&](int k0, int bufo) {
        #pragma unroll
        for (int t = 0; t < 4; ++t) {
            const int row = w * 32 + t * 8 + lr8;
            const int gc = ((l8 ^ (row & 7)) << 3);
            dma16(A + (size_t)(m0 + row) * D_ + k0 + gc, &smem[bufo + row * 64 + l8 * 8]);
        }
        #pragma unroll
        for (int t = 0; t < 2; ++t) {
            const int row = w * 16 + t * 8 + lr8;
            const int gc = ((l8 ^ (row & 7)) << 3);
            dma16(BTi + (size_t)(n0 + row) * D_ + k0 + gc, &smem[bufo + 8192 + row * 64 + l8 * 8]);
            dma16(BTg + (size_t)(n0 + row) * D_ + k0 + gc, &smem[bufo + 12288 + row * 64 + l8 * 8]);
        }
    };

    stage(0, 0);
    __syncthreads();
    for (int t = 0; t < 16; ++t) {
        const int bufo = (t & 1) * 16384;
        if (t < 15) stage((t + 1) * 64, 16384 - bufo);
        const ushort_t* As = smem + bufo;
        const ushort_t* Bi = smem + bufo + 8192;
        const ushort_t* Bg = smem + bufo + 12288;
        #pragma unroll
        for (int kk = 0; kk < 2; ++kk) {
            bf16x8 af[4], bfi[2], bfg[2];
            #pragma unroll
            for (int i = 0; i < 4; ++i)
                af[i] = fragr(As, wr + 16 * i + l15, kk * 4 + quad);
            #pragma unroll
            for (int j = 0; j < 2; ++j) {
                bfi[j] = fragr(Bi, wc + 16 * j + l15, kk * 4 + quad);
                bfg[j] = fragr(Bg, wc + 16 * j + l15, kk * 4 + quad);
            }
            #pragma unroll
            for (int i = 0; i < 4; ++i)
                #pragma unroll
                for (int j = 0; j < 2; ++j) {
                    acc_i[i][j] = __builtin_amdgcn_mfma_f32_16x16x32_bf16(
                        af[i], bfi[j], acc_i[i][j], 0, 0, 0);
                    acc_g[i][j] = __builtin_amdgcn_mfma_f32_16x16x32_bf16(
                        af[i], bfg[j], acc_g[i][j], 0, 0, 0);
                }
        }
        __syncthreads();
    }

    // epilogue: reuse staging LDS. Us bf16, Gu u16 fixed-point gate.
    ushort_t* Us = smem;
    ushort_t* Gu = smem + 8448;
    #pragma unroll
    for (int j = 0; j < 2; ++j) {
        const int n = wc + 16 * j + l15;
        const float bbi = bi[n0 + n], bbg = bg[n0 + n];
        #pragma unroll
        for (int i = 0; i < 4; ++i) {
            #pragma unroll
            for (int r = 0; r < 4; ++r) {
                const int m = wr + 16 * i + quad * 4 + r;
                Us[m * 66 + n] = f2bf(acc_i[i][j][r] + bbi);
                float g = 1.0f / (1.0f + __expf(-(acc_g[i][j][r] + bbg)));
                Gu[m * 66 + n] = (ushort_t)__float2uint_rn(g * 65535.0f);
            }
        }
    }
    __syncthreads();

    const int nl = tid & 63, c = tid >> 6;
    const int gmb = m0 + c * 32;
    const size_t gbase = (size_t)gmb * D_ + n0 + nl;
    float Aa = 1.0f, hh = 0.0f;
    #pragma unroll 4
    for (int j = 0; j < 32; ++j) {
        const float g = (float)Gu[(c * 32 + j) * 66 + nl] * (1.0f / 65535.0f);
        const float u = bf2f(Us[(c * 32 + j) * 66 + nl]);
        Aa *= g;
        hh = fmaf(g, hh, u);
        PH[gbase + (size_t)j * D_] = (uint_t)f2bf(Aa) | ((uint_t)f2bf(hh) << 16);
    }
    const int bb = gmb >> 11;
    const int ch = (gmb & 2047) >> 5;
    const int ci = ((bb * 64 + ch) << 10) + n0 + nl;
    cA[ci] = Aa;
    cU[ci] = hh;
}

// ---------------------------------------------------------------------------
// mid_scan: blocks [0,512) = state scan, 1 float/thread (4x waves vs float4
// variant -> G loads fully prefetch under the serial fma chain);
// blocks [512,520) = chunk-level gated scan -> carry-ins.
// ---------------------------------------------------------------------------
__global__ __launch_bounds__(256)
void mid_scan(const float* __restrict__ Gg, const float* __restrict__ gammas,
              ushort_t* __restrict__ Sb, const float* __restrict__ cA,
              const float* __restrict__ cU, float* __restrict__ cIn) {
    const int bi = blockIdx.x;
    if (bi < 512) {
        const int bh = bi >> 4;                 // (b*H + h) in [0,32)
        const int h = bh & 15;
        const int e = (bi & 15) * 256 + threadIdx.x;   // entry in [0,4096)
        const float g64 = exp2f(64.0f * log2f(gammas[h]));
        const size_t base = (size_t)bh * 32 * 4096 + e;
        float S = 0.0f;
        #pragma unroll
        for (int c = 0; c < 32; ++c) {
            Sb[base + (size_t)c * 4096] = f2bf(S);
            const float G = Gg[base + (size_t)c * 4096];
            S = g64 * (S + G);
        }
        return;
    }
    const int t = (bi - 512) * 256 + threadIdx.x;   // 0..2047
    const int d = t & 1023, b = t >> 10;
    float h = 0.0f;
    for (int c0 = 0; c0 < 64; c0 += 16) {
        float Av[16], Uv[16];
        #pragma unroll
        for (int j = 0; j < 16; ++j) {
            const int idx = ((b * 64 + c0 + j) << 10) + d;
            Av[j] = cA[idx]; Uv[j] = cU[idx];
        }
        #pragma unroll
        for (int j = 0; j < 16; ++j) {
            cIn[((b * 64 + c0 + j) << 10) + d] = h;
            h = fmaf(Av[j], h, Uv[j]);
        }
    }
}

// ---------------------------------------------------------------------------
// Elementwise fix: h = h_local + cIn[chunk] * P  -> bf16 (packed PH input)
// ---------------------------------------------------------------------------
__global__ __launch_bounds__(256)
void scan_fix(const uint_t* __restrict__ PH, const float* __restrict__ cIn,
              ushort_t* __restrict__ hout) {
    const int i = (blockIdx.x * 256 + threadIdx.x) * 4;
    const int m = i >> 10, d = i & 1023;
    const int b = m >> 11, ch = (m & 2047) >> 5;
    uint4 ph = *(const uint4*)(PH + i);
    float4 ci = *(const float4*)(cIn + ((b * 64 + ch) << 10) + d);
    ushort4 o;
    o.x = f2bf(fmaf(ci.x, bf2f((ushort_t)(ph.x & 0xFFFF)), bf2f((ushort_t)(ph.x >> 16))));
    o.y = f2bf(fmaf(ci.y, bf2f((ushort_t)(ph.y & 0xFFFF)), bf2f((ushort_t)(ph.y >> 16))));
    o.z = f2bf(fmaf(ci.z, bf2f((ushort_t)(ph.z & 0xFFFF)), bf2f((ushort_t)(ph.z >> 16))));
    o.w = f2bf(fmaf(ci.w, bf2f((ushort_t)(ph.w & 0xFFFF)), bf2f((ushort_t)(ph.w >> 16))));
    *(ushort4*)(hout + i) = o;
}

// ---------------------------------------------------------------------------
// Fused W_out GEMM + retention, XCD-swizzled, with hidden retention staging
// (round-5/9 verbatim: A staged via global_load_lds from h_bf).
// ---------------------------------------------------------------------------
__global__ __launch_bounds__(256)
void gemm_out_ret(const ushort_t* __restrict__ A, const ushort_t* __restrict__ BT,
                  const float* __restrict__ bias, const ushort_t* __restrict__ Kb,
                  const ushort_t* __restrict__ VT, const ushort_t* __restrict__ Sb,
                  const float* __restrict__ gammas, float* __restrict__ Out) {
    __shared__ ushort_t smem[24576];   // 48 KB
    const int tid = threadIdx.x;
    const int flat = blockIdx.x + (blockIdx.y << 4);
    const int swz = (flat & 7) * 64 + (flat >> 3);
    const int h = swz & 15;                   // head
    const int n0 = h * 64, m0 = (swz >> 4) * 128;
    const int w = tid >> 6, lane = tid & 63, quad = lane >> 4, l15 = lane & 15;
    const int wr = (w >> 1) * 64, wc = (w & 1) * 32;
    const int l8 = lane & 7, lr8 = lane >> 3;

    ushort_t* Qs = smem;
    ushort_t* Ks = smem + 8192;
    ushort_t* Vt = smem + 12288;
    ushort_t* Ss = smem + 16384;
    ushort_t* Ps = smem + 20480;

    auto stageK = [&](int sc) {
        const int mrow = m0 + sc * 64;
        const size_t bS2 = (size_t)(mrow >> 11) * S_;
        const int s0r = mrow & 2047;
        #pragma unroll
        for (int t2 = 0; t2 < 2; ++t2) {
            const int row = w * 16 + t2 * 8 + lr8;
            const int gc = ((l8 ^ (row & 7)) << 3);
            dma16(Kb + (bS2 + s0r + row) * D_ + h * HD_ + gc, &Ks[row * 64 + l8 * 8]);
        }
    };
    auto stageV = [&](int sc) {
        const int mrow = m0 + sc * 64;
        const size_t vrow0 = (size_t)(((mrow >> 11) * H_ + h) * HD_);
        const int s0r = mrow & 2047;
        #pragma unroll
        for (int t2 = 0; t2 < 2; ++t2) {
            const int row = w * 16 + t2 * 8 + lr8;
            const int gc = ((l8 ^ (row & 7)) << 3);
            dma16(VT + (vrow0 + row) * S_ + s0r + gc, &Vt[row * 64 + l8 * 8]);
        }
    };
    auto stageS = [&](int sc) {
        const int mrow = m0 + sc * 64;
        const size_t sbase = ((size_t)(((mrow >> 11) * H_ + h) * 32 + ((mrow & 2047) >> 6))) * 4096;
        #pragma unroll
        for (int t2 = 0; t2 < 2; ++t2) {
            const int row = w * 16 + t2 * 8 + lr8;
            const int gc = ((l8 ^ (row & 7)) << 3);
            dma16(Sb + sbase + (size_t)row * 64 + gc, &Ss[row * 64 + l8 * 8]);
        }
    };

    f32x4 acc[4][2] = {};

    auto stage = [&](int k0, int bufo) {
        #pragma unroll
        for (int t = 0; t < 4; ++t) {
            const int row = w * 32 + t * 8 + lr8;
            const int gc = ((l8 ^ (row & 7)) << 3);
            dma16(A + (size_t)(m0 + row) * D_ + k0 + gc, &smem[bufo + row * 64 + l8 * 8]);
        }
        #pragma unroll
        for (int t = 0; t < 2; ++t) {
            const int row = w * 16 + t * 8 + lr8;
            const int gc = ((l8 ^ (row & 7)) << 3);
            dma16(BT + (size_t)(n0 + row) * D_ + k0 + gc, &smem[bufo + 8192 + row * 64 + l8 * 8]);
        }
    };

    stage(0, 0);
    __syncthreads();
    for (int t = 0; t < 16; ++t) {
        const int bufo = (t & 1) * 12288;
        if (t < 15) stage((t + 1) * 64, 12288 - bufo);
        if (t == 15) stageK(0);   // buffer0 Bs region (== Ks) dead since t=14 sync
        const ushort_t* As = smem + bufo;
        const ushort_t* Bs = smem + bufo + 8192;
        #pragma unroll
        for (int kk = 0; kk < 2; ++kk) {
            bf16x8 af[4], bf[2];
            #pragma unroll
            for (int i = 0; i < 4; ++i)
                af[i] = fragr(As, wr + 16 * i + l15, kk * 4 + quad);
            #pragma unroll
            for (int j = 0; j < 2; ++j)
                bf[j] = fragr(Bs, wc + 16 * j + l15, kk * 4 + quad);
            #pragma unroll
            for (int i = 0; i < 4; ++i)
                #pragma unroll
                for (int j = 0; j < 2; ++j)
                    acc[i][j] = __builtin_amdgcn_mfma_f32_16x16x32_bf16(
                        af[i], bf[j], acc[i][j], 0, 0, 0);
        }
        __syncthreads();
    }

    // buffer1 dead after the final sync: issue chunk-0 V/S staging now.
    stageV(0);
    stageS(0);

    // ---- qp -> Qs (retention fragment layout, swizzled) --------------------
    #pragma unroll
    for (int j = 0; j < 2; ++j) {
        const int n = wc + 16 * j + l15;
        const float bb = bias[n0 + n];
        #pragma unroll
        for (int i = 0; i < 4; ++i)
            #pragma unroll
            for (int r = 0; r < 4; ++r) {
                const int m = wr + 16 * i + quad * 4 + r;
                Qs[m * 64 + (((n >> 3) ^ (m & 7)) << 3) + (n & 7)] =
                    f2bf((acc[i][j][r] + bb) * 0.125f);
            }
    }

    const float lg = log2f(gammas[h]);
    const int nl = w * 16 + l15;

    for (int sc = 0; sc < 2; ++sc) {
        __syncthreads();   // staged K/V/S (and Qs writes) visible; vmcnt drained
        const int mrow = m0 + sc * 64;
        const size_t bS = (size_t)(mrow >> 11) * S_;
        const int s0 = mrow & 2047;
        const ushort_t* Qsub = Qs + sc * 64 * 64;

        bf16x8 qf0 = fragr(Qsub, nl, quad);
        bf16x8 qf1 = fragr(Qsub, nl, 4 + quad);

        f32x4 o[4] = {};
        #pragma unroll
        for (int ct = 0; ct < 4; ++ct) {
            bf16x8 sf0 = fragr(Ss, ct * 16 + l15, quad);
            bf16x8 sf1 = fragr(Ss, ct * 16 + l15, 4 + quad);
            o[ct] = __builtin_amdgcn_mfma_f32_16x16x32_bf16(sf0, qf0, o[ct], 0, 0, 0);
            o[ct] = __builtin_amdgcn_mfma_f32_16x16x32_bf16(sf1, qf1, o[ct], 0, 0, 0);
        }
        uint2 pw[4];
        #pragma unroll
        for (int mt2 = 0; mt2 < 4; ++mt2) {
            bf16x8 kf0 = fragr(Ks, mt2 * 16 + l15, quad);
            bf16x8 kf1 = fragr(Ks, mt2 * 16 + l15, 4 + quad);
            f32x4 s = {};
            s = __builtin_amdgcn_mfma_f32_16x16x32_bf16(kf0, qf0, s, 0, 0, 0);
            s = __builtin_amdgcn_mfma_f32_16x16x32_bf16(kf1, qf1, s, 0, 0, 0);
            const int mbase = mt2 * 16 + quad * 4;
            #pragma unroll
            for (int r = 0; r < 4; ++r)
                if (nl < mbase + r) s[r] = 0.0f;
            pw[mt2].x = pkt(s[0], s[1]); pw[mt2].y = pkt(s[2], s[3]);
        }
        __syncthreads();   // all waves done reading Ks/Ss
        if (sc == 0) { stageK(1); stageS(1); }
        #pragma unroll
        for (int mt2 = 0; mt2 < 4; ++mt2) {
            const int mbase = mt2 * 16 + quad * 4;
            const int chunk = mbase >> 3;
            *(uint2*)&Ps[nl * 64 + ((chunk ^ (nl & 7)) << 3) + (mbase & 7)] = pw[mt2];
        }
        bf16x8 pf0 = fragr(Ps, nl, quad);
        bf16x8 pf1 = fragr(Ps, nl, 4 + quad);
        #pragma unroll
        for (int ct = 0; ct < 4; ++ct) {
            bf16x8 vf0 = fragr(Vt, ct * 16 + l15, quad);
            bf16x8 vf1 = fragr(Vt, ct * 16 + l15, 4 + quad);
            o[ct] = __builtin_amdgcn_mfma_f32_16x16x32_bf16(vf0, pf0, o[ct], 0, 0, 0);
            o[ct] = __builtin_amdgcn_mfma_f32_16x16x32_bf16(vf1, pf1, o[ct], 0, 0, 0);
        }

        const float esc = exp2f((float)nl * lg);
        const size_t ob = (bS + s0 + nl) * D_ + h * HD_;
        #pragma unroll
        for (int ct = 0; ct < 4; ++ct) {
            f32x4 t = o[ct] * esc;
            *(f32x4*)(Out + ob + ct * 16 + quad * 4) = t;
        }
        __syncthreads();   // all waves done reading Vt/Ps
        if (sc == 0) stageV(1);
    }
}

// ---------------------------------------------------------------------------
extern "C" void kernel_launch(void* const* d_in, const int* in_sizes, int n_in,
                              void* d_out, int out_size, void* d_ws, size_t ws_size,
                              hipStream_t stream) {
    const float* q      = (const float*)d_in[0];
    const float* k      = (const float*)d_in[1];
    const float* v      = (const float*)d_in[2];
    const float* W_in   = (const float*)d_in[3];
    const float* b_in   = (const float*)d_in[4];
    const float* W_gate = (const float*)d_in[5];
    const float* b_gate = (const float*)d_in[6];
    const float* W_out  = (const float*)d_in[7];
    const float* b_out  = (const float*)d_in[8];
    const float* gammas = (const float*)d_in[9];
    float* out = (float*)d_out;

    char* ws = (char*)d_ws;
    const size_t MB = 1024 * 1024;
    uint_t*   PH      = (uint_t*)(ws);                // [0,16) packed (P, h_local)
    ushort_t* h_bf    = (ushort_t*)(ws + 24 * MB);    // [24,32)
    ushort_t* q_bf    = (ushort_t*)(ws + 32 * MB);    // [32,40)
    ushort_t* WT_in   = (ushort_t*)(ws + 40 * MB);
    ushort_t* WT_gate = (ushort_t*)(ws + 42 * MB);
    ushort_t* WT_out  = (ushort_t*)(ws + 44 * MB);
    float*    cA      = (float*)(ws + 46 * MB);
    float*    cU      = (float*)(ws + 46 * MB + 512 * 1024);
    float*    cIn     = (float*)(ws + 47 * MB);
    ushort_t* k_bf    = (ushort_t*)(ws + 48 * MB);    // [48,56)
    ushort_t* VT      = (ushort_t*)(ws + 56 * MB);    // [56,64)
    float*    Gg      = (float*)(ws + 64 * MB);       // [64,80)
    ushort_t* Sb      = (ushort_t*)(ws + 80 * MB);    // [80,88)

    prep<<<3072 + (M_ * D_) / (256 * 4), 256, 0, stream>>>(
        W_in, W_gate, W_out, WT_in, WT_gate, WT_out, q, q_bf);

    gemm_dual_kv<<<512 + 1024, 256, 0, stream>>>(
        q_bf, WT_in, WT_gate, b_in, b_gate, PH, cA, cU,
        k, v, gammas, k_bf, VT, Gg);

    mid_scan<<<520, 256, 0, stream>>>(Gg, gammas, Sb, cA, cU, cIn);
    scan_fix<<<(M_ * D_) / 1024, 256, 0, stream>>>(PH, cIn, h_bf);

    gemm_out_ret<<<dim3(H_, M_ / 128), 256, 0, stream>>>(
        h_bf, WT_out, b_out, k_bf, VT, Sb, gammas, out);
}

// Round 12
// 174.160 us; speedup vs baseline: 1.0995x; 1.0240x over previous
//
#include <hip/hip_runtime.h>
#include <math.h>

#define B_  2
#define S_  2048
#define D_  1024
#define H_  16
#define HD_ 64
#define M_  (B_*S_)

typedef unsigned short ushort_t;
typedef unsigned int   uint_t;
typedef __attribute__((ext_vector_type(8))) short bf16x8;
typedef __attribute__((ext_vector_type(4))) float f32x4;

__device__ __forceinline__ ushort_t f2bf(float f) {
    uint_t u = __builtin_bit_cast(uint_t, f);
    u += 0x7FFFu + ((u >> 16) & 1u);           // RNE
    return (ushort_t)(u >> 16);
}
__device__ __forceinline__ float bf2f(ushort_t h) {
    uint_t u = (uint_t)h << 16;
    return __builtin_bit_cast(float, u);
}
// truncating pack: two f32 -> (bf16(lo) | bf16(hi)<<16), one v_perm_b32
__device__ __forceinline__ uint_t pkt(float lo, float hi) {
    return __builtin_amdgcn_perm(__builtin_bit_cast(uint_t, hi),
                                 __builtin_bit_cast(uint_t, lo), 0x07060302u);
}
// async global->LDS, 16B per lane; lds addr = wave-uniform base + lane*16
__device__ __forceinline__ void dma16(const ushort_t* g, ushort_t* l) {
    __builtin_amdgcn_global_load_lds(
        (const __attribute__((address_space(1))) uint_t*)g,
        (__attribute__((address_space(3))) uint_t*)l, 16, 0, 0);
}
// swizzled fragment read from unpadded [row][64] bf16 tile
__device__ __forceinline__ bf16x8 fragr(const ushort_t* base, int row, int chunk) {
    return *(const bf16x8*)&base[row * 64 + (((chunk ^ (row & 7)) << 3))];
}

// ---------------------------------------------------------------------------
// prep: blocks [0,3072) = weight transpose+cvt (W [K][N] f32 -> WT [N][K] bf16)
//       blocks [3072,7168) = q f32 -> bf16
// ---------------------------------------------------------------------------
__global__ __launch_bounds__(256)
void prep(const float* __restrict__ W0, const float* __restrict__ W1,
          const float* __restrict__ W2, ushort_t* __restrict__ T0,
          ushort_t* __restrict__ T1, ushort_t* __restrict__ T2,
          const float* __restrict__ X, ushort_t* __restrict__ Y) {
    const int bx = blockIdx.x;
    if (bx >= 3072) {
        const int i = ((bx - 3072) * 256 + threadIdx.x) * 4;
        float4 x = *(const float4*)(X + i);
        *(ushort4*)(Y + i) = make_ushort4(f2bf(x.x), f2bf(x.y), f2bf(x.z), f2bf(x.w));
        return;
    }
    __shared__ float T[32][36];
    const int z = bx >> 10;
    const float*  W  = (z == 0) ? W0 : (z == 1) ? W1 : W2;
    ushort_t*     WT = (z == 0) ? T0 : (z == 1) ? T1 : T2;
    const int kt = bx & 31, nt = (bx >> 5) & 31;
    const int t = threadIdx.x;
    const int rr = t >> 3, cc = (t & 7) * 4;
    float4 w4 = *(const float4*)(W + (size_t)(kt * 32 + rr) * D_ + nt * 32 + cc);
    T[rr][cc + 0] = w4.x; T[rr][cc + 1] = w4.y; T[rr][cc + 2] = w4.z; T[rr][cc + 3] = w4.w;
    __syncthreads();
    ushort_t o[4];
    #pragma unroll
    for (int j = 0; j < 4; ++j) o[j] = f2bf(T[cc + j][rr]);
    *(ushort4*)(WT + (size_t)(nt * 32 + rr) * D_ + kt * 32 + cc) =
        make_ushort4(o[0], o[1], o[2], o[3]);
}

// ---------------------------------------------------------------------------
// Merged launch: blocks [0,512) = fused dual GEMM + chunk-scan epilogue
// (XCD-swizzled); blocks [512,1536) = kv_cvt_g (inputs-only, backfills the
// latency-bound dual — its memory traffic rides in the dual's BW headroom).
// ---------------------------------------------------------------------------
__global__ __launch_bounds__(256)
void gemm_dual_kv(const ushort_t* __restrict__ A, const ushort_t* __restrict__ BTi,
                  const ushort_t* __restrict__ BTg, const float* __restrict__ bi,
                  const float* __restrict__ bg, uint_t* __restrict__ PH,
                  float* __restrict__ cA, float* __restrict__ cU,
                  const float* __restrict__ K, const float* __restrict__ V,
                  const float* __restrict__ gammas, ushort_t* __restrict__ Kb,
                  ushort_t* __restrict__ VT, float* __restrict__ Gg) {
    __shared__ ushort_t smem[32768];   // 64 KB
    const int tid = threadIdx.x;
    const int w = tid >> 6, lane = tid & 63, quad = lane >> 4, l15 = lane & 15;

    if (blockIdx.x >= 512) {
        // ---------------- kv_cvt_g role ----------------
        ushort_t* Tv = smem;               // [val][ml]  64*72
        ushort_t* Tk = smem + 64 * 72;     // [kappa][ml] 64*72
        const int idx = blockIdx.x - 512;
        const int mt = idx & 31, h = (idx >> 5) & 15, b = idx >> 9;
        const int m0 = mt * 64;
        const int r = tid >> 2, c0 = (tid & 3) * 16;
        const float lg = log2f(gammas[h]);
        const float gm = exp2f(-(float)r * lg);   // gamma^{-ml}, ml = r
        {
            const float* src = K + ((size_t)(b * S_ + m0 + r)) * D_ + h * HD_ + c0;
            ushort_t kb[16];
            #pragma unroll
            for (int j4 = 0; j4 < 4; ++j4) {
                float4 x = *(const float4*)(src + j4 * 4);
                kb[j4 * 4 + 0] = f2bf(x.x); kb[j4 * 4 + 1] = f2bf(x.y);
                kb[j4 * 4 + 2] = f2bf(x.z); kb[j4 * 4 + 3] = f2bf(x.w);
            }
            ushort_t* dst = Kb + ((size_t)(b * S_ + m0 + r)) * D_ + h * HD_ + c0;
            *(uint4*)(dst + 0) = *(const uint4*)&kb[0];
            *(uint4*)(dst + 8) = *(const uint4*)&kb[8];
            #pragma unroll
            for (int j = 0; j < 16; ++j) Tk[(c0 + j) * 72 + r] = kb[j];
        }
        {
            const float* src = V + ((size_t)(b * S_ + m0 + r)) * D_ + h * HD_ + c0;
            #pragma unroll
            for (int j4 = 0; j4 < 4; ++j4) {
                float4 x = *(const float4*)(src + j4 * 4);
                Tv[(c0 + j4 * 4 + 0) * 72 + r] = f2bf(x.x * gm);
                Tv[(c0 + j4 * 4 + 1) * 72 + r] = f2bf(x.y * gm);
                Tv[(c0 + j4 * 4 + 2) * 72 + r] = f2bf(x.z * gm);
                Tv[(c0 + j4 * 4 + 3) * 72 + r] = f2bf(x.w * gm);
            }
        }
        __syncthreads();
        {
            ushort_t* dst = VT + ((size_t)((b * H_ + h) * HD_ + r)) * S_ + m0 + c0;
            *(uint4*)(dst + 0) = *(const uint4*)&Tv[r * 72 + c0 + 0];
            *(uint4*)(dst + 8) = *(const uint4*)&Tv[r * 72 + c0 + 8];
        }
        // G^T = Tv . Tk^T via MFMA
        bf16x8 af0 = *(const bf16x8*)&Tv[(w * 16 + l15) * 72 + quad * 8];
        bf16x8 af1 = *(const bf16x8*)&Tv[(w * 16 + l15) * 72 + 32 + quad * 8];
        float* gout = Gg + ((size_t)((b * H_ + h) * 32 + mt)) * 4096;
        #pragma unroll
        for (int kt2 = 0; kt2 < 4; ++kt2) {
            bf16x8 bf0 = *(const bf16x8*)&Tk[(kt2 * 16 + l15) * 72 + quad * 8];
            bf16x8 bf1 = *(const bf16x8*)&Tk[(kt2 * 16 + l15) * 72 + 32 + quad * 8];
            f32x4 g = {};
            g = __builtin_amdgcn_mfma_f32_16x16x32_bf16(af0, bf0, g, 0, 0, 0);
            g = __builtin_amdgcn_mfma_f32_16x16x32_bf16(af1, bf1, g, 0, 0, 0);
            #pragma unroll
            for (int reg = 0; reg < 4; ++reg)
                gout[(w * 16 + quad * 4 + reg) * 64 + kt2 * 16 + l15] = g[reg];
        }
        return;
    }

    // ---------------- dual GEMM + scan role --------------
    const int swz = (blockIdx.x & 7) * 64 + (blockIdx.x >> 3);
    const int n0 = (swz & 15) * 64, m0 = (swz >> 4) * 128;
    const int wr = (w >> 1) * 64, wc = (w & 1) * 32;
    const int l8 = lane & 7, lr8 = lane >> 3;

    f32x4 acc_i[4][2] = {};
    f32x4 acc_g[4][2] = {};

    auto stage = [&](int k0, int bufo) {
        #pragma unroll
        for (int t = 0; t < 4; ++t) {
            const int row = w * 32 + t * 8 + lr8;
            const int gc = ((l8 ^ (row & 7)) << 3);
            dma16(A + (size_t)(m0 + row) * D_ + k0 + gc, &smem[bufo + row * 64 + l8 * 8]);
        }
        #pragma unroll
        for (int t = 0; t < 2; ++t) {
            const int row = w * 16 + t * 8 + lr8;
            const int gc = ((l8 ^ (row & 7)) << 3);
            dma16(BTi + (size_t)(n0 + row) * D_ + k0 + gc, &smem[bufo + 8192 + row * 64 + l8 * 8]);
            dma16(BTg + (size_t)(n0 + row) * D_ + k0 + gc, &smem[bufo + 12288 + row * 64 + l8 * 8]);
        }
    };

    stage(0, 0);
    __syncthreads();
    for (int t = 0; t < 16; ++t) {
        const int bufo = (t & 1) * 16384;
        if (t < 15) stage((t + 1) * 64, 16384 - bufo);
        const ushort_t* As = smem + bufo;
        const ushort_t* Bi = smem + bufo + 8192;
        const ushort_t* Bg = smem + bufo + 12288;
        #pragma unroll
        for (int kk = 0; kk < 2; ++kk) {
            bf16x8 af[4], bfi[2], bfg[2];
            #pragma unroll
            for (int i = 0; i < 4; ++i)
                af[i] = fragr(As, wr + 16 * i + l15, kk * 4 + quad);
            #pragma unroll
            for (int j = 0; j < 2; ++j) {
                bfi[j] = fragr(Bi, wc + 16 * j + l15, kk * 4 + quad);
                bfg[j] = fragr(Bg, wc + 16 * j + l15, kk * 4 + quad);
            }
            #pragma unroll
            for (int i = 0; i < 4; ++i)
                #pragma unroll
                for (int j = 0; j < 2; ++j) {
                    acc_i[i][j] = __builtin_amdgcn_mfma_f32_16x16x32_bf16(
                        af[i], bfi[j], acc_i[i][j], 0, 0, 0);
                    acc_g[i][j] = __builtin_amdgcn_mfma_f32_16x16x32_bf16(
                        af[i], bfg[j], acc_g[i][j], 0, 0, 0);
                }
        }
        __syncthreads();
    }

    // epilogue: reuse staging LDS. Us bf16, Gu u16 fixed-point gate.
    ushort_t* Us = smem;
    ushort_t* Gu = smem + 8448;
    #pragma unroll
    for (int j = 0; j < 2; ++j) {
        const int n = wc + 16 * j + l15;
        const float bbi = bi[n0 + n], bbg = bg[n0 + n];
        #pragma unroll
        for (int i = 0; i < 4; ++i) {
            #pragma unroll
            for (int r = 0; r < 4; ++r) {
                const int m = wr + 16 * i + quad * 4 + r;
                Us[m * 66 + n] = f2bf(acc_i[i][j][r] + bbi);
                float g = 1.0f / (1.0f + __expf(-(acc_g[i][j][r] + bbg)));
                Gu[m * 66 + n] = (ushort_t)__float2uint_rn(g * 65535.0f);
            }
        }
    }
    __syncthreads();

    const int nl = tid & 63, c = tid >> 6;
    const int gmb = m0 + c * 32;
    const size_t gbase = (size_t)gmb * D_ + n0 + nl;
    float Aa = 1.0f, hh = 0.0f;
    #pragma unroll 4
    for (int j = 0; j < 32; ++j) {
        const float g = (float)Gu[(c * 32 + j) * 66 + nl] * (1.0f / 65535.0f);
        const float u = bf2f(Us[(c * 32 + j) * 66 + nl]);
        Aa *= g;
        hh = fmaf(g, hh, u);
        PH[gbase + (size_t)j * D_] = (uint_t)f2bf(Aa) | ((uint_t)f2bf(hh) << 16);
    }
    const int bb = gmb >> 11;
    const int ch = (gmb & 2047) >> 5;
    const int ci = ((bb * 64 + ch) << 10) + n0 + nl;
    cA[ci] = Aa;
    cU[ci] = hh;
}

// ---------------------------------------------------------------------------
// Merged mid-kernels: blocks [0,128) = state scan (S_c = g64*(S_{c-1}+G), f32
// G input, bf16 S out, float4/thread); blocks [128,136) = chunk-level gated
// scan -> carry-ins.
// ---------------------------------------------------------------------------
__global__ __launch_bounds__(256)
void mid_scan(const float* __restrict__ Gg, const float* __restrict__ gammas,
              ushort_t* __restrict__ Sb, const float* __restrict__ cA,
              const float* __restrict__ cU, float* __restrict__ cIn) {
    const int bi = blockIdx.x;
    if (bi < 128) {
        const int sl = bi & 3, h = (bi >> 2) & 15, b = bi >> 6;
        const float g64 = exp2f(64.0f * log2f(gammas[h]));
        const int r = threadIdx.x >> 4;
        const int cb = (threadIdx.x & 15) * 4;
        const size_t base = ((size_t)((b * H_ + h) * 32)) * 4096 + (sl * 16 + r) * 64 + cb;
        float4 S = make_float4(0.f, 0.f, 0.f, 0.f);
        for (int c = 0; c < 32; ++c) {
            ushort4 sb;
            sb.x = f2bf(S.x); sb.y = f2bf(S.y); sb.z = f2bf(S.z); sb.w = f2bf(S.w);
            *(ushort4*)(Sb + base + (size_t)c * 4096) = sb;
            float4 G = *(const float4*)(Gg + base + (size_t)c * 4096);
            S.x = g64 * (S.x + G.x); S.y = g64 * (S.y + G.y);
            S.z = g64 * (S.z + G.z); S.w = g64 * (S.w + G.w);
        }
        return;
    }
    const int t = (bi - 128) * 256 + threadIdx.x;   // 0..2047
    const int d = t & 1023, b = t >> 10;
    float h = 0.0f;
    for (int c0 = 0; c0 < 64; c0 += 16) {
        float Av[16], Uv[16];
        #pragma unroll
        for (int j = 0; j < 16; ++j) {
            const int idx = ((b * 64 + c0 + j) << 10) + d;
            Av[j] = cA[idx]; Uv[j] = cU[idx];
        }
        #pragma unroll
        for (int j = 0; j < 16; ++j) {
            cIn[((b * 64 + c0 + j) << 10) + d] = h;
            h = fmaf(Av[j], h, Uv[j]);
        }
    }
}

// ---------------------------------------------------------------------------
// Elementwise fix: h = h_local + cIn[chunk] * P  -> bf16 (packed PH input)
// ---------------------------------------------------------------------------
__global__ __launch_bounds__(256)
void scan_fix(const uint_t* __restrict__ PH, const float* __restrict__ cIn,
              ushort_t* __restrict__ hout) {
    const int i = (blockIdx.x * 256 + threadIdx.x) * 4;
    const int m = i >> 10, d = i & 1023;
    const int b = m >> 11, ch = (m & 2047) >> 5;
    uint4 ph = *(const uint4*)(PH + i);
    float4 ci = *(const float4*)(cIn + ((b * 64 + ch) << 10) + d);
    ushort4 o;
    o.x = f2bf(fmaf(ci.x, bf2f((ushort_t)(ph.x & 0xFFFF)), bf2f((ushort_t)(ph.x >> 16))));
    o.y = f2bf(fmaf(ci.y, bf2f((ushort_t)(ph.y & 0xFFFF)), bf2f((ushort_t)(ph.y >> 16))));
    o.z = f2bf(fmaf(ci.z, bf2f((ushort_t)(ph.z & 0xFFFF)), bf2f((ushort_t)(ph.z >> 16))));
    o.w = f2bf(fmaf(ci.w, bf2f((ushort_t)(ph.w & 0xFFFF)), bf2f((ushort_t)(ph.w >> 16))));
    *(ushort4*)(hout + i) = o;
}

// ---------------------------------------------------------------------------
// Fused W_out GEMM + retention, XCD-swizzled, with hidden retention staging
// (round-5/9 verbatim: A staged via global_load_lds from h_bf).
// ---------------------------------------------------------------------------
__global__ __launch_bounds__(256)
void gemm_out_ret(const ushort_t* __restrict__ A, const ushort_t* __restrict__ BT,
                  const float* __restrict__ bias, const ushort_t* __restrict__ Kb,
                  const ushort_t* __restrict__ VT, const ushort_t* __restrict__ Sb,
                  const float* __restrict__ gammas, float* __restrict__ Out) {
    __shared__ ushort_t smem[24576];   // 48 KB
    const int tid = threadIdx.x;
    const int flat = blockIdx.x + (blockIdx.y << 4);
    const int swz = (flat & 7) * 64 + (flat >> 3);
    const int h = swz & 15;                   // head
    const int n0 = h * 64, m0 = (swz >> 4) * 128;
    const int w = tid >> 6, lane = tid & 63, quad = lane >> 4, l15 = lane & 15;
    const int wr = (w >> 1) * 64, wc = (w & 1) * 32;
    const int l8 = lane & 7, lr8 = lane >> 3;

    ushort_t* Qs = smem;
    ushort_t* Ks = smem + 8192;
    ushort_t* Vt = smem + 12288;
    ushort_t* Ss = smem + 16384;
    ushort_t* Ps = smem + 20480;

    auto stageK = [&](int sc) {
        const int mrow = m0 + sc * 64;
        const size_t bS2 = (size_t)(mrow >> 11) * S_;
        const int s0r = mrow & 2047;
        #pragma unroll
        for (int t2 = 0; t2 < 2; ++t2) {
            const int row = w * 16 + t2 * 8 + lr8;
            const int gc = ((l8 ^ (row & 7)) << 3);
            dma16(Kb + (bS2 + s0r + row) * D_ + h * HD_ + gc, &Ks[row * 64 + l8 * 8]);
        }
    };
    auto stageV = [&](int sc) {
        const int mrow = m0 + sc * 64;
        const size_t vrow0 = (size_t)(((mrow >> 11) * H_ + h) * HD_);
        const int s0r = mrow & 2047;
        #pragma unroll
        for (int t2 = 0; t2 < 2; ++t2) {
            const int row = w * 16 + t2 * 8 + lr8;
            const int gc = ((l8 ^ (row & 7)) << 3);
            dma16(VT + (vrow0 + row) * S_ + s0r + gc, &Vt[row * 64 + l8 * 8]);
        }
    };
    auto stageS = [&](int sc) {
        const int mrow = m0 + sc * 64;
        const size_t sbase = ((size_t)(((mrow >> 11) * H_ + h) * 32 + ((mrow & 2047) >> 6))) * 4096;
        #pragma unroll
        for (int t2 = 0; t2 < 2; ++t2) {
            const int row = w * 16 + t2 * 8 + lr8;
            const int gc = ((l8 ^ (row & 7)) << 3);
            dma16(Sb + sbase + (size_t)row * 64 + gc, &Ss[row * 64 + l8 * 8]);
        }
    };

    f32x4 acc[4][2] = {};

    auto stage = [&](int k0, int bufo) {
        #pragma unroll
        for (int t = 0; t < 4; ++t) {
            const int row = w * 32 + t * 8 + lr8;
            const int gc = ((l8 ^ (row & 7)) << 3);
            dma16(A + (size_t)(m0 + row) * D_ + k0 + gc, &smem[bufo + row * 64 + l8 * 8]);
        }
        #pragma unroll
        for (int t = 0; t < 2; ++t) {
            const int row = w * 16 + t * 8 + lr8;
            const int gc = ((l8 ^ (row & 7)) << 3);
            dma16(BT + (size_t)(n0 + row) * D_ + k0 + gc, &smem[bufo + 8192 + row * 64 + l8 * 8]);
        }
    };

    stage(0, 0);
    __syncthreads();
    for (int t = 0; t < 16; ++t) {
        const int bufo = (t & 1) * 12288;
        if (t < 15) stage((t + 1) * 64, 12288 - bufo);
        if (t == 15) stageK(0);   // buffer0 Bs region (== Ks) dead since t=14 sync
        const ushort_t* As = smem + bufo;
        const ushort_t* Bs = smem + bufo + 8192;
        #pragma unroll
        for (int kk = 0; kk < 2; ++kk) {
            bf16x8 af[4], bf[2];
            #pragma unroll
            for (int i = 0; i < 4; ++i)
                af[i] = fragr(As, wr + 16 * i + l15, kk * 4 + quad);
            #pragma unroll
            for (int j = 0; j < 2; ++j)
                bf[j] = fragr(Bs, wc + 16 * j + l15, kk * 4 + quad);
            #pragma unroll
            for (int i = 0; i < 4; ++i)
                #pragma unroll
                for (int j = 0; j < 2; ++j)
                    acc[i][j] = __builtin_amdgcn_mfma_f32_16x16x32_bf16(
                        af[i], bf[j], acc[i][j], 0, 0, 0);
        }
        __syncthreads();
    }

    // buffer1 dead after the final sync: issue chunk-0 V/S staging now.
    stageV(0);
    stageS(0);

    // ---- qp -> Qs (retention fragment layout, swizzled) --------------------
    #pragma unroll
    for (int j = 0; j < 2; ++j) {
        const int n = wc + 16 * j + l15;
        const float bb = bias[n0 + n];
        #pragma unroll
        for (int i = 0; i < 4; ++i)
            #pragma unroll
            for (int r = 0; r < 4; ++r) {
                const int m = wr + 16 * i + quad * 4 + r;
                Qs[m * 64 + (((n >> 3) ^ (m & 7)) << 3) + (n & 7)] =
                    f2bf((acc[i][j][r] + bb) * 0.125f);
            }
    }

    const float lg = log2f(gammas[h]);
    const int nl = w * 16 + l15;

    for (int sc = 0; sc < 2; ++sc) {
        __syncthreads();   // staged K/V/S (and Qs writes) visible; vmcnt drained
        const int mrow = m0 + sc * 64;
        const size_t bS = (size_t)(mrow >> 11) * S_;
        const int s0 = mrow & 2047;
        const ushort_t* Qsub = Qs + sc * 64 * 64;

        bf16x8 qf0 = fragr(Qsub, nl, quad);
        bf16x8 qf1 = fragr(Qsub, nl, 4 + quad);

        f32x4 o[4] = {};
        #pragma unroll
        for (int ct = 0; ct < 4; ++ct) {
            bf16x8 sf0 = fragr(Ss, ct * 16 + l15, quad);
            bf16x8 sf1 = fragr(Ss, ct * 16 + l15, 4 + quad);
            o[ct] = __builtin_amdgcn_mfma_f32_16x16x32_bf16(sf0, qf0, o[ct], 0, 0, 0);
            o[ct] = __builtin_amdgcn_mfma_f32_16x16x32_bf16(sf1, qf1, o[ct], 0, 0, 0);
        }
        uint2 pw[4];
        #pragma unroll
        for (int mt2 = 0; mt2 < 4; ++mt2) {
            bf16x8 kf0 = fragr(Ks, mt2 * 16 + l15, quad);
            bf16x8 kf1 = fragr(Ks, mt2 * 16 + l15, 4 + quad);
            f32x4 s = {};
            s = __builtin_amdgcn_mfma_f32_16x16x32_bf16(kf0, qf0, s, 0, 0, 0);
            s = __builtin_amdgcn_mfma_f32_16x16x32_bf16(kf1, qf1, s, 0, 0, 0);
            const int mbase = mt2 * 16 + quad * 4;
            #pragma unroll
            for (int r = 0; r < 4; ++r)
                if (nl < mbase + r) s[r] = 0.0f;
            pw[mt2].x = pkt(s[0], s[1]); pw[mt2].y = pkt(s[2], s[3]);
        }
        __syncthreads();   // all waves done reading Ks/Ss
        if (sc == 0) { stageK(1); stageS(1); }
        #pragma unroll
        for (int mt2 = 0; mt2 < 4; ++mt2) {
            const int mbase = mt2 * 16 + quad * 4;
            const int chunk = mbase >> 3;
            *(uint2*)&Ps[nl * 64 + ((chunk ^ (nl & 7)) << 3) + (mbase & 7)] = pw[mt2];
        }
        bf16x8 pf0 = fragr(Ps, nl, quad);
        bf16x8 pf1 = fragr(Ps, nl, 4 + quad);
        #pragma unroll
        for (int ct = 0; ct < 4; ++ct) {
            bf16x8 vf0 = fragr(Vt, ct * 16 + l15, quad);
            bf16x8 vf1 = fragr(Vt, ct * 16 + l15, 4 + quad);
            o[ct] = __builtin_amdgcn_mfma_f32_16x16x32_bf16(vf0, pf0, o[ct], 0, 0, 0);
            o[ct] = __builtin_amdgcn_mfma_f32_16x16x32_bf16(vf1, pf1, o[ct], 0, 0, 0);
        }

        const float esc = exp2f((float)nl * lg);
        const size_t ob = (bS + s0 + nl) * D_ + h * HD_;
        #pragma unroll
        for (int ct = 0; ct < 4; ++ct) {
            f32x4 t = o[ct] * esc;
            *(f32x4*)(Out + ob + ct * 16 + quad * 4) = t;
        }
        __syncthreads();   // all waves done reading Vt/Ps
        if (sc == 0) stageV(1);
    }
}

// ---------------------------------------------------------------------------
extern "C" void kernel_launch(void* const* d_in, const int* in_sizes, int n_in,
                              void* d_out, int out_size, void* d_ws, size_t ws_size,
                              hipStream_t stream) {
    const float* q      = (const float*)d_in[0];
    const float* k      = (const float*)d_in[1];
    const float* v      = (const float*)d_in[2];
    const float* W_in   = (const float*)d_in[3];
    const float* b_in   = (const float*)d_in[4];
    const float* W_gate = (const float*)d_in[5];
    const float* b_gate = (const float*)d_in[6];
    const float* W_out  = (const float*)d_in[7];
    const float* b_out  = (const float*)d_in[8];
    const float* gammas = (const float*)d_in[9];
    float* out = (float*)d_out;

    char* ws = (char*)d_ws;
    const size_t MB = 1024 * 1024;
    uint_t*   PH      = (uint_t*)(ws);                // [0,16) packed (P, h_local)
    ushort_t* h_bf    = (ushort_t*)(ws + 24 * MB);    // [24,32)
    ushort_t* q_bf    = (ushort_t*)(ws + 32 * MB);    // [32,40)
    ushort_t* WT_in   = (ushort_t*)(ws + 40 * MB);
    ushort_t* WT_gate = (ushort_t*)(ws + 42 * MB);
    ushort_t* WT_out  = (ushort_t*)(ws + 44 * MB);
    float*    cA      = (float*)(ws + 46 * MB);
    float*    cU      = (float*)(ws + 46 * MB + 512 * 1024);
    float*    cIn     = (float*)(ws + 47 * MB);
    ushort_t* k_bf    = (ushort_t*)(ws + 48 * MB);    // [48,56)
    ushort_t* VT      = (ushort_t*)(ws + 56 * MB);    // [56,64)
    float*    Gg      = (float*)(ws + 64 * MB);       // [64,80)
    ushort_t* Sb      = (ushort_t*)(ws + 80 * MB);    // [80,88)

    prep<<<3072 + (M_ * D_) / (256 * 4), 256, 0, stream>>>(
        W_in, W_gate, W_out, WT_in, WT_gate, WT_out, q, q_bf);

    gemm_dual_kv<<<512 + 1024, 256, 0, stream>>>(
        q_bf, WT_in, WT_gate, b_in, b_gate, PH, cA, cU,
        k, v, gammas, k_bf, VT, Gg);

    mid_scan<<<136, 256, 0, stream>>>(Gg, gammas, Sb, cA, cU, cIn);
    scan_fix<<<(M_ * D_) / 1024, 256, 0, stream>>>(PH, cIn, h_bf);

    gemm_out_ret<<<dim3(H_, M_ / 128), 256, 0, stream>>>(
        h_bf, WT_out, b_out, k_bf, VT, Sb, gammas, out);
}